// Round 2
// baseline (1321.799 us; speedup 1.0000x reference)
//
#include <hip/hip_runtime.h>

#define N_RELS 16
#define N_BASES 8
#define HD 128
#define CHUNKS 32

typedef __attribute__((ext_vector_type(8))) short bf16x8;
typedef __attribute__((ext_vector_type(4))) float floatx4;

__device__ __forceinline__ short bf16rn(float f) {
    union { float f; unsigned u; } v; v.f = f;
    unsigned u = v.u;
    unsigned r = (u + 0x7fffu + ((u >> 16) & 1u)) >> 16;
    return (short)r;
}
__device__ __forceinline__ float bf16f(short s) {
    union { unsigned u; float f; } v; v.u = ((unsigned)(unsigned short)s) << 16;
    return v.f;
}

// ---------------- bucketing: group edges by relation ----------------

__global__ void count_etype(const int* __restrict__ etype, int E, int* __restrict__ counts) {
    __shared__ int lh[N_RELS];
    if (threadIdx.x < N_RELS) lh[threadIdx.x] = 0;
    __syncthreads();
    for (int e = blockIdx.x * blockDim.x + threadIdx.x; e < E; e += gridDim.x * blockDim.x)
        atomicAdd(&lh[etype[e]], 1);
    __syncthreads();
    if (threadIdx.x < N_RELS) atomicAdd(&counts[threadIdx.x], lh[threadIdx.x]);
}

__global__ void scan16(const int* __restrict__ counts, int* __restrict__ offsets,
                       int* __restrict__ cursor) {
    if (threadIdx.x == 0 && blockIdx.x == 0) {
        int s = 0;
        for (int r = 0; r < N_RELS; r++) { offsets[r] = s; cursor[r] = s; s += counts[r]; }
        offsets[N_RELS] = s;
    }
}

// scatter edge data into relation-sorted arrays (fused permutation)
__global__ void scatter_edges(const int* __restrict__ etype, const int* __restrict__ src,
                              const int* __restrict__ dst, const float* __restrict__ norm,
                              int E, int* __restrict__ cursor,
                              int* __restrict__ srcp, int* __restrict__ dstp,
                              float* __restrict__ normp) {
    __shared__ int lh[N_RELS];
    __shared__ int lbase[N_RELS];
    int t = threadIdx.x;
    if (t < N_RELS) lh[t] = 0;
    __syncthreads();
    int e = blockIdx.x * blockDim.x + t;
    int r = 0, lpos = 0;
    bool valid = e < E;
    if (valid) { r = etype[e]; lpos = atomicAdd(&lh[r], 1); }
    __syncthreads();
    if (t < N_RELS) lbase[t] = atomicAdd(&cursor[t], lh[t]);
    __syncthreads();
    if (valid) {
        int p = lbase[r] + lpos;
        srcp[p] = src[e];
        dstp[p] = dst[e];
        normp[p] = norm[e];
    }
}

// ---------------- W[r] = sum_b coef[r,b]*V[b], emitted in MFMA B-fragment order,
// bf16 hi/lo split. Frag layout for 16x16x32: lane holds B[n=lane&15][k=(lane>>4)*8+j].
// Flat idx within relation: ((kk*8 + t)*64 + lane)*8 + j, n = t*16+(lane&15), k = kk*32+...

__global__ void compute_W_frags(const float* __restrict__ V1, const float* __restrict__ coef1,
                                const float* __restrict__ V2, const float* __restrict__ coef2,
                                short* __restrict__ Wf_hi, short* __restrict__ Wf_lo) {
    int blk = blockIdx.x;          // 0..31 = layer*16 + rel
    int l = blk >> 4, r = blk & 15;
    const float* V    = l ? V2 : V1;
    const float* coef = l ? coef2 : coef1;
    __shared__ float c[N_BASES];
    if (threadIdx.x < N_BASES) c[threadIdx.x] = coef[r * N_BASES + threadIdx.x];
    __syncthreads();
    size_t obase = (size_t)blk * 16384;
    for (int e = threadIdx.x; e < 16384; e += blockDim.x) {
        float w = 0.f;
#pragma unroll
        for (int b = 0; b < N_BASES; b++) w += c[b] * V[b * 16384 + e];
        int k = e >> 7, n = e & 127;
        int kk = k >> 5, q = (k >> 3) & 3, j = k & 7;
        int tt = n >> 4, cc = n & 15;
        int lane = q * 16 + cc;
        int idx = ((kk * 8 + tt) * 64 + lane) * 8 + j;
        short hb = bf16rn(w);
        Wf_hi[obase + idx] = hb;
        Wf_lo[obase + idx] = bf16rn(w - bf16f(hb));
    }
}

// ---------------- init: x[n,:] = bias ----------------

__global__ void init_bias(float* __restrict__ x, const float* __restrict__ bias, int n4) {
    int i = blockIdx.x * blockDim.x + threadIdx.x;
    if (i < n4) ((float4*)x)[i] = ((const float4*)bias)[i & 31];
}

// ---------------- edge kernel: per-wave 16-edge MFMA GEMM + atomic scatter ----------------
// grid = 16 rels x CHUNKS, block = 512 (8 waves). LDS = 64KB W-frags (hi+lo) -> 2 blocks/CU.
// VGPR <= 128 via launch_bounds -> 16 waves/CU. No barriers in the main loop.

__global__ __launch_bounds__(512, 4) void edge_mfma(
    const float* __restrict__ hin, const short* __restrict__ Whi,
    const short* __restrict__ Wlo, const float* __restrict__ normp,
    const int* __restrict__ srcp, const int* __restrict__ dstp,
    const int* __restrict__ offsets, float* __restrict__ out, int relu) {
    __shared__ __align__(16) short Bs[2][4][8][64][8];   // [hi/lo][kk][t][lane][j] = 64 KB
    const int r = blockIdx.x & 15;
    const int chunk = blockIdx.x >> 4;
    const int t0 = threadIdx.x;

    {   // stage W frags: 4096 float4s across 512 threads
        float4* bsv = (float4*)&Bs[0][0][0][0][0];
        const float4* gh = (const float4*)(Whi + (size_t)r * 16384);
        const float4* gl = (const float4*)(Wlo + (size_t)r * 16384);
#pragma unroll
        for (int i = 0; i < 4; i++) bsv[t0 + i * 512] = gh[t0 + i * 512];
#pragma unroll
        for (int i = 0; i < 4; i++) bsv[2048 + t0 + i * 512] = gl[t0 + i * 512];
    }
    __syncthreads();

    const int wave = t0 >> 6, lane = t0 & 63;
    const int q = lane >> 4, cc = lane & 15;
    const int begin = offsets[r], end = offsets[r + 1];
    const int gw = chunk * 8 + wave;
    const int gstride = CHUNKS * 8;

    for (int base = begin + gw * 16; base < end; base += gstride * 16) {
        // ---- gather A rows, split to bf16 hi/lo frags: m = lane&15, k = q*8+j (+32*kk)
        int em = base + cc;
        bool v = em < end;
        int e = v ? em : begin;
        int s = srcp[e];
        float nv = v ? normp[e] : 0.f;
        const float* row = hin + (size_t)s * HD;
        bf16x8 Ahi[4], Alo[4];
#pragma unroll
        for (int kk = 0; kk < 4; kk++) {
            float4 x0 = *(const float4*)(row + kk * 32 + q * 8);
            float4 x1 = *(const float4*)(row + kk * 32 + q * 8 + 4);
            float xs[8] = {x0.x, x0.y, x0.z, x0.w, x1.x, x1.y, x1.z, x1.w};
#pragma unroll
            for (int j = 0; j < 8; j++) {
                float x = relu ? fmaxf(xs[j], 0.f) : xs[j];
                x *= nv;
                short hb = bf16rn(x);
                Ahi[kk][j] = hb;
                Alo[kk][j] = bf16rn(x - bf16f(hb));
            }
        }

        floatx4 acc[8] = {};
#pragma unroll
        for (int kk = 0; kk < 4; kk++) {
#pragma unroll
            for (int t = 0; t < 8; t++) {
                bf16x8 bh = *(const bf16x8*)&Bs[0][kk][t][lane][0];
                bf16x8 bl = *(const bf16x8*)&Bs[1][kk][t][lane][0];
                acc[t] = __builtin_amdgcn_mfma_f32_16x16x32_bf16(Ahi[kk], bh, acc[t], 0, 0, 0);
                acc[t] = __builtin_amdgcn_mfma_f32_16x16x32_bf16(Alo[kk], bh, acc[t], 0, 0, 0);
                acc[t] = __builtin_amdgcn_mfma_f32_16x16x32_bf16(Ahi[kk], bl, acc[t], 0, 0, 0);
            }
        }

        // ---- scatter: C/D layout col = lane&15, row(m) = q*4 + reg
        int de[4]; bool dv[4];
#pragma unroll
        for (int i = 0; i < 4; i++) {
            int eidx = base + q * 4 + i;
            dv[i] = eidx < end;
            de[i] = dv[i] ? dstp[eidx] : 0;
        }
#pragma unroll
        for (int t = 0; t < 8; t++) {
#pragma unroll
            for (int i = 0; i < 4; i++) {
                if (dv[i]) unsafeAtomicAdd(&out[(size_t)de[i] * HD + t * 16 + cc], acc[t][i]);
            }
        }
    }
}

// ---------------- launch ----------------

extern "C" void kernel_launch(void* const* d_in, const int* in_sizes, int n_in,
                              void* d_out, int out_size, void* d_ws, size_t ws_size,
                              hipStream_t stream) {
    const float* h     = (const float*)d_in[0];
    const float* norm  = (const float*)d_in[1];
    const int*   src   = (const int*)d_in[2];
    const int*   dst   = (const int*)d_in[3];
    const int*   etype = (const int*)d_in[4];
    const float* V1    = (const float*)d_in[5];
    const float* coef1 = (const float*)d_in[6];
    const float* bias1 = (const float*)d_in[7];
    const float* V2    = (const float*)d_in[8];
    const float* coef2 = (const float*)d_in[9];
    const float* bias2 = (const float*)d_in[10];
    const int N = in_sizes[0] / HD;
    const int E = in_sizes[2];
    float* out = (float*)d_out;

    char* ws = (char*)d_ws;
    size_t off = 0;
    auto alloc = [&](size_t bytes) {
        void* p = ws + off;
        off += (bytes + 255) & ~(size_t)255;
        return p;
    };
    short* Wf_hi  = (short*)alloc((size_t)32 * 16384 * sizeof(short));
    short* Wf_lo  = (short*)alloc((size_t)32 * 16384 * sizeof(short));
    float* h1     = (float*)alloc((size_t)N * HD * sizeof(float));
    int*   srcp   = (int*)alloc((size_t)E * sizeof(int));
    int*   dstp   = (int*)alloc((size_t)E * sizeof(int));
    float* normp  = (float*)alloc((size_t)E * sizeof(float));
    int*   counts  = (int*)alloc(16 * sizeof(int));
    int*   offsets = (int*)alloc(17 * sizeof(int));
    int*   cursor  = (int*)alloc(16 * sizeof(int));
    (void)ws_size; (void)n_in; (void)out_size;

    hipMemsetAsync(counts, 0, 16 * sizeof(int), stream);

    count_etype<<<(E + 255) / 256, 256, 0, stream>>>(etype, E, counts);
    scan16<<<1, 64, 0, stream>>>(counts, offsets, cursor);
    scatter_edges<<<(E + 255) / 256, 256, 0, stream>>>(etype, src, dst, norm, E, cursor,
                                                       srcp, dstp, normp);
    compute_W_frags<<<32, 256, 0, stream>>>(V1, coef1, V2, coef2, Wf_hi, Wf_lo);
    init_bias<<<(N * HD / 4 + 255) / 256, 256, 0, stream>>>(h1, bias1, N * HD / 4);
    init_bias<<<(N * HD / 4 + 255) / 256, 256, 0, stream>>>(out, bias2, N * HD / 4);

    // layer 1: h1 = bias1 + scatter(msg);  (relu deferred to layer-2 gather)
    edge_mfma<<<N_RELS * CHUNKS, 512, 0, stream>>>(h, Wf_hi, Wf_lo, normp, srcp, dstp,
                                                   offsets, h1, 0);
    // layer 2: out = bias2 + scatter(msg over relu(h1))
    edge_mfma<<<N_RELS * CHUNKS, 512, 0, stream>>>(h1, Wf_hi + 16 * 16384, Wf_lo + 16 * 16384,
                                                   normp, srcp, dstp, offsets, out, 1);
}

// Round 3
// 673.137 us; speedup vs baseline: 1.9636x; 1.9636x over previous
//
#include <hip/hip_runtime.h>

#define N_RELS 16
#define N_BASES 8
#define HD 128
#define SCAN_B 1024

typedef __attribute__((ext_vector_type(8))) short bf16x8;
typedef __attribute__((ext_vector_type(4))) float floatx4;

__device__ __forceinline__ short bf16rn(float f) {
    union { float f; unsigned u; } v; v.f = f;
    unsigned u = v.u;
    unsigned r = (u + 0x7fffu + ((u >> 16) & 1u)) >> 16;
    return (short)r;
}
__device__ __forceinline__ float bf16f(short s) {
    union { unsigned u; float f; } v; v.u = ((unsigned)(unsigned short)s) << 16;
    return v.f;
}

// ---------------- dst counting-sort: hist -> scan -> scatter (CSR) ----------------

__global__ void hist_dst(const int* __restrict__ dst, int E, int* __restrict__ cnt) {
    int i = blockIdx.x * blockDim.x + threadIdx.x;
    if (i < E) atomicAdd(&cnt[dst[i]], 1);
}

__global__ void scan_partial(const int* __restrict__ cnt, int N,
                             int* __restrict__ excl, int* __restrict__ bsum) {
    __shared__ int s[SCAN_B];
    int t = threadIdx.x, i = blockIdx.x * SCAN_B + t;
    int v = (i < N) ? cnt[i] : 0;
    s[t] = v; __syncthreads();
    for (int o = 1; o < SCAN_B; o <<= 1) {
        int x = (t >= o) ? s[t - o] : 0;
        __syncthreads();
        s[t] += x;
        __syncthreads();
    }
    if (i < N) excl[i] = s[t] - v;
    if (t == SCAN_B - 1) bsum[blockIdx.x] = s[t];
}

__global__ void scan_bsum(int* __restrict__ bsum, int nb, int* __restrict__ row_ptr,
                          int N, int E) {
    if (threadIdx.x == 0 && blockIdx.x == 0) {
        int run = 0;
        for (int b = 0; b < nb; b++) { int x = bsum[b]; bsum[b] = run; run += x; }
        row_ptr[N] = E;
    }
}

__global__ void scan_fixup(int* __restrict__ row_ptr, const int* __restrict__ bsum,
                           int N, int* __restrict__ cursor) {
    int i = blockIdx.x * blockDim.x + threadIdx.x;
    if (i < N) { int v = row_ptr[i] + bsum[i >> 10]; row_ptr[i] = v; cursor[i] = v; }
}

__global__ void scatter_dst(const int* __restrict__ dst, const int* __restrict__ src,
                            const int* __restrict__ et, const float* __restrict__ norm,
                            int E, int N, int* __restrict__ cursor, int2* __restrict__ edata) {
    int i = blockIdx.x * blockDim.x + threadIdx.x;
    if (i >= E) return;
    int p = atomicAdd(&cursor[dst[i]], 1);
    edata[p] = make_int2(et[i] * N + src[i], __float_as_int(norm[i]));
}

// ---------------- W[r] = sum_b coef[r,b]*V[b] in MFMA B-frag order, bf16 hi/lo ----------------
// (verified in R2) frag: lane holds B[n=lane&15][k=(lane>>4)*8+j]

__global__ void compute_W_frags(const float* __restrict__ V1, const float* __restrict__ coef1,
                                const float* __restrict__ V2, const float* __restrict__ coef2,
                                short* __restrict__ Wf_hi, short* __restrict__ Wf_lo) {
    int blk = blockIdx.x;          // 0..31 = layer*16 + rel
    int l = blk >> 4, r = blk & 15;
    const float* V    = l ? V2 : V1;
    const float* coef = l ? coef2 : coef1;
    __shared__ float c[N_BASES];
    if (threadIdx.x < N_BASES) c[threadIdx.x] = coef[r * N_BASES + threadIdx.x];
    __syncthreads();
    size_t obase = (size_t)blk * 16384;
    for (int e = threadIdx.x; e < 16384; e += blockDim.x) {
        float w = 0.f;
#pragma unroll
        for (int b = 0; b < N_BASES; b++) w += c[b] * V[b * 16384 + e];
        int k = e >> 7, n = e & 127;
        int kk = k >> 5, q = (k >> 3) & 3, j = k & 7;
        int tt = n >> 4, cc = n & 15;
        int lane = q * 16 + cc;
        int idx = ((kk * 8 + tt) * 64 + lane) * 8 + j;
        short hb = bf16rn(w);
        Wf_hi[obase + idx] = hb;
        Wf_lo[obase + idx] = bf16rn(w - bf16f(hb));
    }
}

// ---------------- phase 1: Hr[rel] = (relu?)(hin) @ W[rel], dense, 16 rows/wave ----------------
// grid = G rels x 391 m-blocks; block 512 (8 waves); LDS 64KB B-frags -> 2 blocks/CU.

__global__ __launch_bounds__(512, 4) void hr_gemm(
    const float* __restrict__ hin, const short* __restrict__ Whi,
    const short* __restrict__ Wlo, float* __restrict__ Hr,
    int relu, int G, int N) {
    __shared__ __align__(16) short Bs[2][4][8][64][8];   // [hi/lo][kk][t][lane][j] = 64 KB
    const int rel = blockIdx.x % G;
    const int blkm = blockIdx.x / G;
    const int t0 = threadIdx.x;

    {   // stage W frags for this rel
        float4* bsv = (float4*)&Bs[0][0][0][0][0];
        const float4* gh = (const float4*)(Whi + (size_t)rel * 16384);
        const float4* gl = (const float4*)(Wlo + (size_t)rel * 16384);
#pragma unroll
        for (int i = 0; i < 4; i++) bsv[t0 + i * 512] = gh[t0 + i * 512];
#pragma unroll
        for (int i = 0; i < 4; i++) bsv[2048 + t0 + i * 512] = gl[t0 + i * 512];
    }
    __syncthreads();

    const int wave = t0 >> 6, lane = t0 & 63;
    const int q = lane >> 4, cc = lane & 15;
    const int mt = blkm * 8 + wave;            // 16-row tile id
    if (mt * 16 >= N) return;                  // whole-wave exit; no barriers after

    // ---- A frags: row = mt*16 + cc (N % 16 == 0), k = kk*32 + q*8 + j
    const float* row = hin + (size_t)(mt * 16 + cc) * HD;
    bf16x8 Ahi[4], Alo[4];
#pragma unroll
    for (int kk = 0; kk < 4; kk++) {
        float4 x0 = *(const float4*)(row + kk * 32 + q * 8);
        float4 x1 = *(const float4*)(row + kk * 32 + q * 8 + 4);
        float xs[8] = {x0.x, x0.y, x0.z, x0.w, x1.x, x1.y, x1.z, x1.w};
#pragma unroll
        for (int j = 0; j < 8; j++) {
            float x = relu ? fmaxf(xs[j], 0.f) : xs[j];
            short hb = bf16rn(x);
            Ahi[kk][j] = hb;
            Alo[kk][j] = bf16rn(x - bf16f(hb));
        }
    }

    floatx4 acc[8] = {};
#pragma unroll
    for (int kk = 0; kk < 4; kk++) {
#pragma unroll
        for (int t = 0; t < 8; t++) {
            bf16x8 bh = *(const bf16x8*)&Bs[0][kk][t][lane][0];
            bf16x8 bl = *(const bf16x8*)&Bs[1][kk][t][lane][0];
            acc[t] = __builtin_amdgcn_mfma_f32_16x16x32_bf16(Ahi[kk], bh, acc[t], 0, 0, 0);
            acc[t] = __builtin_amdgcn_mfma_f32_16x16x32_bf16(Alo[kk], bh, acc[t], 0, 0, 0);
            acc[t] = __builtin_amdgcn_mfma_f32_16x16x32_bf16(Ahi[kk], bl, acc[t], 0, 0, 0);
        }
    }

    // ---- store: C/D layout col = t*16 + (lane&15), row(m) = q*4 + reg
    float* orow = Hr + (size_t)rel * N * HD;
#pragma unroll
    for (int t = 0; t < 8; t++)
#pragma unroll
        for (int i = 0; i < 4; i++)
            orow[(size_t)(mt * 16 + q * 4 + i) * HD + t * 16 + cc] = acc[t][i];
}

// ---------------- phase 2: out[d] = (first? bias : out[d]) + sum_e norm*Hr[rowidx] ----------------
// one wave per destination node; zero atomics.

__global__ __launch_bounds__(256) void seg_agg(
    const float* __restrict__ Hr, const int2* __restrict__ edata,
    const int* __restrict__ row_ptr, const float* __restrict__ bias,
    float* __restrict__ out, int N, int rlo, int rhi, int first) {
    int wid = (blockIdx.x * blockDim.x + threadIdx.x) >> 6;
    int lane = threadIdx.x & 63;
    if (wid >= N) return;
    int e = row_ptr[wid], end = row_ptr[wid + 1];
    float ax = 0.f, ay = 0.f;

    for (; e + 4 <= end; e += 4) {
        int2 m0 = edata[e], m1 = edata[e + 1], m2 = edata[e + 2], m3 = edata[e + 3];
#pragma unroll
        for (int j = 0; j < 4; j++) {
            int2 m = j == 0 ? m0 : j == 1 ? m1 : j == 2 ? m2 : m3;
            if (m.x >= rlo && m.x < rhi) {
                const float2 v = *(const float2*)(Hr + (size_t)(m.x - rlo) * HD + lane * 2);
                float nv = __int_as_float(m.y);
                ax = fmaf(v.x, nv, ax);
                ay = fmaf(v.y, nv, ay);
            }
        }
    }
    for (; e < end; e++) {
        int2 m = edata[e];
        if (m.x >= rlo && m.x < rhi) {
            const float2 v = *(const float2*)(Hr + (size_t)(m.x - rlo) * HD + lane * 2);
            float nv = __int_as_float(m.y);
            ax = fmaf(v.x, nv, ax);
            ay = fmaf(v.y, nv, ay);
        }
    }

    size_t o = (size_t)wid * HD + lane * 2;
    float2 res;
    if (first) {
        res.x = ax + bias[lane * 2];
        res.y = ay + bias[lane * 2 + 1];
    } else {
        float2 p = *(const float2*)&out[o];
        res.x = p.x + ax;
        res.y = p.y + ay;
    }
    *(float2*)&out[o] = res;
}

// ---------------- launch ----------------

extern "C" void kernel_launch(void* const* d_in, const int* in_sizes, int n_in,
                              void* d_out, int out_size, void* d_ws, size_t ws_size,
                              hipStream_t stream) {
    const float* h     = (const float*)d_in[0];
    const float* norm  = (const float*)d_in[1];
    const int*   src   = (const int*)d_in[2];
    const int*   dst   = (const int*)d_in[3];
    const int*   etype = (const int*)d_in[4];
    const float* V1    = (const float*)d_in[5];
    const float* coef1 = (const float*)d_in[6];
    const float* bias1 = (const float*)d_in[7];
    const float* V2    = (const float*)d_in[8];
    const float* coef2 = (const float*)d_in[9];
    const float* bias2 = (const float*)d_in[10];
    const int N = in_sizes[0] / HD;   // 50000
    const int E = in_sizes[2];        // 640000
    float* out = (float*)d_out;
    (void)n_in; (void)out_size;

    char* ws = (char*)d_ws;
    size_t off = 0;
    auto alloc = [&](size_t bytes) {
        void* p = ws + off;
        off += (bytes + 255) & ~(size_t)255;
        return p;
    };
    short* Wf_hi   = (short*)alloc((size_t)32 * 16384 * sizeof(short));
    short* Wf_lo   = (short*)alloc((size_t)32 * 16384 * sizeof(short));
    float* h1      = (float*)alloc((size_t)N * HD * sizeof(float));
    int2*  edata   = (int2*)alloc((size_t)E * sizeof(int2));
    int*   cnt     = (int*)alloc((size_t)N * sizeof(int));
    int*   row_ptr = (int*)alloc((size_t)(N + 1) * sizeof(int));
    int*   cursor  = (int*)alloc((size_t)N * sizeof(int));
    int*   bsum    = (int*)alloc(256 * sizeof(int));

    // Hr slab: G relations at a time, G chosen from remaining workspace
    size_t slab = (size_t)N * HD * sizeof(float);   // 25.6 MB per relation
    int G = 16;
    while (G > 1 && off + (size_t)G * slab > ws_size) G >>= 1;
    float* Hr = (float*)alloc((size_t)G * slab);

    const int nb = (N + SCAN_B - 1) / SCAN_B;

    hipMemsetAsync(cnt, 0, (size_t)N * sizeof(int), stream);
    hist_dst<<<(E + 255) / 256, 256, 0, stream>>>(dst, E, cnt);
    scan_partial<<<nb, SCAN_B, 0, stream>>>(cnt, N, row_ptr, bsum);
    scan_bsum<<<1, 64, 0, stream>>>(bsum, nb, row_ptr, N, E);
    scan_fixup<<<(N + 255) / 256, 256, 0, stream>>>(row_ptr, bsum, N, cursor);
    scatter_dst<<<(E + 255) / 256, 256, 0, stream>>>(dst, src, etype, norm, E, N, cursor, edata);
    compute_W_frags<<<32, 256, 0, stream>>>(V1, coef1, V2, coef2, Wf_hi, Wf_lo);

    const int mblocks = ((N / 16) + 7) / 8;          // 391
    const int aggblocks = (N * 64 + 255) / 256;      // 12500

    for (int layer = 0; layer < 2; layer++) {
        const float* hin = layer ? h1 : h;
        float* o         = layer ? out : h1;
        const float* bs  = layer ? bias2 : bias1;
        for (int g = 0; g < N_RELS; g += G) {
            const short* whi = Wf_hi + (size_t)(layer * N_RELS + g) * 16384;
            const short* wlo = Wf_lo + (size_t)(layer * N_RELS + g) * 16384;
            hr_gemm<<<G * mblocks, 512, 0, stream>>>(hin, whi, wlo, Hr, layer, G, N);
            seg_agg<<<aggblocks, 256, 0, stream>>>(Hr, edata, row_ptr, bs, o, N,
                                                   g * N, (g + G) * N, g == 0);
        }
    }
}

// Round 4
// 430.004 us; speedup vs baseline: 3.0739x; 1.5654x over previous
//
#include <hip/hip_runtime.h>

#define N_RELS 16
#define N_BASES 8
#define HD 128
#define SCAN_B 1024

typedef __attribute__((ext_vector_type(8))) short bf16x8;
typedef __attribute__((ext_vector_type(4))) float floatx4;

__device__ __forceinline__ short bf16rn(float f) {
    union { float f; unsigned u; } v; v.f = f;
    unsigned u = v.u;
    unsigned r = (u + 0x7fffu + ((u >> 16) & 1u)) >> 16;
    return (short)r;
}
__device__ __forceinline__ float bf16f(short s) {
    union { unsigned u; float f; } v; v.u = ((unsigned)(unsigned short)s) << 16;
    return v.f;
}

#define GLDS16(g, l)                                                            \
    __builtin_amdgcn_global_load_lds(                                           \
        (const __attribute__((address_space(1))) unsigned*)(g),                 \
        (__attribute__((address_space(3))) unsigned*)(l), 16, 0, 0)

// ---------------- dst counting-sort: hist -> scan -> scatter (CSR) ----------------

__global__ void hist_dst(const int* __restrict__ dst, int E, int* __restrict__ cnt) {
    int i = blockIdx.x * blockDim.x + threadIdx.x;
    if (i < E) atomicAdd(&cnt[dst[i]], 1);
}

__global__ void scan_partial(const int* __restrict__ cnt, int N,
                             int* __restrict__ excl, int* __restrict__ bsum) {
    __shared__ int s[SCAN_B];
    int t = threadIdx.x, i = blockIdx.x * SCAN_B + t;
    int v = (i < N) ? cnt[i] : 0;
    s[t] = v; __syncthreads();
    for (int o = 1; o < SCAN_B; o <<= 1) {
        int x = (t >= o) ? s[t - o] : 0;
        __syncthreads();
        s[t] += x;
        __syncthreads();
    }
    if (i < N) excl[i] = s[t] - v;
    if (t == SCAN_B - 1) bsum[blockIdx.x] = s[t];
}

__global__ void scan_bsum(int* __restrict__ bsum, int nb, int* __restrict__ row_ptr,
                          int N, int E) {
    if (threadIdx.x == 0 && blockIdx.x == 0) {
        int run = 0;
        for (int b = 0; b < nb; b++) { int x = bsum[b]; bsum[b] = run; run += x; }
        row_ptr[N] = E;
    }
}

__global__ void scan_fixup(int* __restrict__ row_ptr, const int* __restrict__ bsum,
                           int N, int* __restrict__ cursor) {
    int i = blockIdx.x * blockDim.x + threadIdx.x;
    if (i < N) { int v = row_ptr[i] + bsum[i >> 10]; row_ptr[i] = v; cursor[i] = v; }
}

// pack (etype, src) into one int: N = 50000 < 65536 so src fits in 16 bits
__global__ void scatter_dst(const int* __restrict__ dst, const int* __restrict__ src,
                            const int* __restrict__ et, const float* __restrict__ norm,
                            int E, int* __restrict__ cursor, int2* __restrict__ edata) {
    int i = blockIdx.x * blockDim.x + threadIdx.x;
    if (i >= E) return;
    int p = atomicAdd(&cursor[dst[i]], 1);
    edata[p] = make_int2((et[i] << 16) | src[i], __float_as_int(norm[i]));
}

// ---------------- V[l][b] -> MFMA B-frag order, bf16 hi/lo ----------------
// frag: lane holds B[n=lane&15][k=(lane>>4)*8+j]; idx = ((kk*8+t)*64+lane)*8+j

__global__ void compute_V_frags(const float* __restrict__ V1, const float* __restrict__ V2,
                                short* __restrict__ Vf_hi, short* __restrict__ Vf_lo) {
    int blk = blockIdx.x;          // 0..15 = layer*8 + basis
    int l = blk >> 3, b = blk & 7;
    const float* V = (l ? V2 : V1) + (size_t)b * 16384;
    size_t obase = (size_t)blk * 16384;
    for (int e = threadIdx.x; e < 16384; e += blockDim.x) {
        float w = V[e];
        int k = e >> 7, n = e & 127;
        int kk = k >> 5, q = (k >> 3) & 3, j = k & 7;
        int tt = n >> 4, cc = n & 15;
        int lane = q * 16 + cc;
        int idx = ((kk * 8 + tt) * 64 + lane) * 8 + j;
        short hb = bf16rn(w);
        Vf_hi[obase + idx] = hb;
        Vf_lo[obase + idx] = bf16rn(w - bf16f(hb));
    }
}

// ---------------- phase 1: Z[d][b][:] = sum_e (coef[et,b]*norm) * act(h[src]) ----------------
// one wave per dst node; fp32 accumulate, bf16 store. Zero atomics.

__global__ __launch_bounds__(256) void basis_agg(
    const float* __restrict__ hin, const int2* __restrict__ edata,
    const int* __restrict__ row_ptr, const float* __restrict__ coef,
    unsigned* __restrict__ Z, int N, int relu) {
    __shared__ float cs[N_RELS * N_BASES];
    if (threadIdx.x < N_RELS * N_BASES) cs[threadIdx.x] = coef[threadIdx.x];
    __syncthreads();

    int wid = (blockIdx.x * blockDim.x + threadIdx.x) >> 6;
    int lane = threadIdx.x & 63;
    if (wid >= N) return;
    int e = row_ptr[wid], end = row_ptr[wid + 1];

    float2 acc[N_BASES] = {};
    for (; e < end; e++) {
        int2 m = edata[e];
        int et = m.x >> 16, s = m.x & 0xffff;
        float nv = __int_as_float(m.y);
        float2 v = *(const float2*)(hin + (size_t)s * HD + lane * 2);
        float vx = relu ? fmaxf(v.x, 0.f) : v.x;
        float vy = relu ? fmaxf(v.y, 0.f) : v.y;
#pragma unroll
        for (int b = 0; b < N_BASES; b++) {
            float w = cs[et * N_BASES + b] * nv;
            acc[b].x = fmaf(vx, w, acc[b].x);
            acc[b].y = fmaf(vy, w, acc[b].y);
        }
    }

    // Z row: [d][b][128] bf16; lane stores cols lane*2, lane*2+1 packed in one uint
    unsigned* zrow = Z + ((size_t)wid * N_BASES * HD + lane * 2) / 2;
#pragma unroll
    for (int b = 0; b < N_BASES; b++) {
        unsigned lo = (unsigned)(unsigned short)bf16rn(acc[b].x);
        unsigned hi = (unsigned)(unsigned short)bf16rn(acc[b].y);
        zrow[b * (HD / 2)] = (hi << 16) | lo;
    }
}

// ---------------- phase 2: out[d] = bias + sum_b Z[d][b] @ V[b] ----------------
// grid 391 blocks x 512 thr (8 waves); K-loop over 8 bases through one 64KB LDS buffer.

__global__ __launch_bounds__(512, 4) void zb_gemm(
    const unsigned short* __restrict__ Z, const short* __restrict__ Vf_hi,
    const short* __restrict__ Vf_lo, const float* __restrict__ bias,
    float* __restrict__ out, int N) {
    __shared__ __align__(16) short Bs[2][4][8][64][8];   // [hi/lo][kk][t][lane][j] = 64 KB
    const int t0 = threadIdx.x;
    const int wave = t0 >> 6, lane = t0 & 63;
    const int q = lane >> 4, cc = lane & 15;
    const int ntiles = N / 16;                 // 3125
    int mt = blockIdx.x * 8 + wave;
    const bool act = mt < ntiles;
    if (!act) mt = 0;                          // clamp; still joins barriers

    const unsigned short* zrow = Z + (size_t)(mt * 16 + cc) * (N_BASES * HD);
    short* lhi = (short*)&Bs[0][0][0][0][0];
    short* llo = (short*)&Bs[1][0][0][0][0];
    const int wl = wave * 64;

    bf16x8 A[4], An[4];
#pragma unroll
    for (int kk = 0; kk < 4; kk++)
        A[kk] = *(const bf16x8*)(zrow + kk * 32 + q * 8);

    floatx4 acc[8] = {};

    for (int b = 0; b < N_BASES; b++) {
        __syncthreads();                       // prior chunk's reads done
        {   // stage basis-b frags (hi+lo, 64 KB) via async global->LDS, 16B/lane
            const short* gh = Vf_hi + (size_t)b * 16384;
            const short* gl = Vf_lo + (size_t)b * 16384;
#pragma unroll
            for (int i = 0; i < 4; i++) {
                GLDS16(gh + (size_t)(i * 512 + wl + lane) * 8, lhi + (size_t)(i * 512 + wl) * 8);
                GLDS16(gl + (size_t)(i * 512 + wl + lane) * 8, llo + (size_t)(i * 512 + wl) * 8);
            }
        }
        __syncthreads();                       // drains vmcnt -> LDS visible

        if (b < N_BASES - 1) {                 // prefetch next A chunk (global, no barrier dep)
#pragma unroll
            for (int kk = 0; kk < 4; kk++)
                An[kk] = *(const bf16x8*)(zrow + (b + 1) * HD + kk * 32 + q * 8);
        }

#pragma unroll
        for (int kk = 0; kk < 4; kk++) {
#pragma unroll
            for (int t = 0; t < 8; t++) {
                bf16x8 bh = *(const bf16x8*)&Bs[0][kk][t][lane][0];
                bf16x8 bl = *(const bf16x8*)&Bs[1][kk][t][lane][0];
                acc[t] = __builtin_amdgcn_mfma_f32_16x16x32_bf16(A[kk], bh, acc[t], 0, 0, 0);
                acc[t] = __builtin_amdgcn_mfma_f32_16x16x32_bf16(A[kk], bl, acc[t], 0, 0, 0);
            }
        }
#pragma unroll
        for (int kk = 0; kk < 4; kk++) A[kk] = An[kk];
    }

    if (act) {
        // C/D layout: col = t*16 + cc, row = q*4 + i
#pragma unroll
        for (int t = 0; t < 8; t++) {
            float bv = bias[t * 16 + cc];
#pragma unroll
            for (int i = 0; i < 4; i++)
                out[(size_t)(mt * 16 + q * 4 + i) * HD + t * 16 + cc] = acc[t][i] + bv;
        }
    }
}

// ---------------- launch ----------------

extern "C" void kernel_launch(void* const* d_in, const int* in_sizes, int n_in,
                              void* d_out, int out_size, void* d_ws, size_t ws_size,
                              hipStream_t stream) {
    const float* h     = (const float*)d_in[0];
    const float* norm  = (const float*)d_in[1];
    const int*   src   = (const int*)d_in[2];
    const int*   dst   = (const int*)d_in[3];
    const int*   etype = (const int*)d_in[4];
    const float* V1    = (const float*)d_in[5];
    const float* coef1 = (const float*)d_in[6];
    const float* bias1 = (const float*)d_in[7];
    const float* V2    = (const float*)d_in[8];
    const float* coef2 = (const float*)d_in[9];
    const float* bias2 = (const float*)d_in[10];
    const int N = in_sizes[0] / HD;   // 50000
    const int E = in_sizes[2];        // 640000
    float* out = (float*)d_out;
    (void)n_in; (void)out_size; (void)ws_size;

    char* ws = (char*)d_ws;
    size_t off = 0;
    auto alloc = [&](size_t bytes) {
        void* p = ws + off;
        off += (bytes + 255) & ~(size_t)255;
        return p;
    };
    short*    Vf_hi   = (short*)alloc((size_t)16 * 16384 * sizeof(short));   // 2 layers x 8 bases
    short*    Vf_lo   = (short*)alloc((size_t)16 * 16384 * sizeof(short));
    float*    h1      = (float*)alloc((size_t)N * HD * sizeof(float));
    int2*     edata   = (int2*)alloc((size_t)E * sizeof(int2));
    int*      cnt     = (int*)alloc((size_t)N * sizeof(int));
    int*      row_ptr = (int*)alloc((size_t)(N + 1) * sizeof(int));
    int*      cursor  = (int*)alloc((size_t)N * sizeof(int));
    int*      bsum    = (int*)alloc(256 * sizeof(int));
    unsigned* Z       = (unsigned*)alloc((size_t)N * N_BASES * HD * sizeof(short)); // 102.4 MB

    const int nb = (N + SCAN_B - 1) / SCAN_B;

    hipMemsetAsync(cnt, 0, (size_t)N * sizeof(int), stream);
    hist_dst<<<(E + 255) / 256, 256, 0, stream>>>(dst, E, cnt);
    scan_partial<<<nb, SCAN_B, 0, stream>>>(cnt, N, row_ptr, bsum);
    scan_bsum<<<1, 64, 0, stream>>>(bsum, nb, row_ptr, N, E);
    scan_fixup<<<(N + 255) / 256, 256, 0, stream>>>(row_ptr, bsum, N, cursor);
    scatter_dst<<<(E + 255) / 256, 256, 0, stream>>>(dst, src, etype, norm, E, cursor, edata);
    compute_V_frags<<<16, 256, 0, stream>>>(V1, V2, Vf_hi, Vf_lo);

    const int aggblocks = (N * 64 + 255) / 256;            // 12500
    const int gemmblocks = ((N / 16) + 7) / 8;             // 391

    // layer 1: h1 = bias1 + sum_b Z_b @ V1_b   (relu deferred to layer-2 gather)
    basis_agg<<<aggblocks, 256, 0, stream>>>(h, edata, row_ptr, coef1, Z, N, 0);
    zb_gemm<<<gemmblocks, 512, 0, stream>>>((const unsigned short*)Z, Vf_hi, Vf_lo,
                                            bias1, h1, N);
    // layer 2: out = bias2 + sum_b Z_b(relu(h1)) @ V2_b
    basis_agg<<<aggblocks, 256, 0, stream>>>(h1, edata, row_ptr, coef2, Z, N, 1);
    zb_gemm<<<gemmblocks, 512, 0, stream>>>((const unsigned short*)Z,
                                            Vf_hi + (size_t)8 * 16384,
                                            Vf_lo + (size_t)8 * 16384, bias2, out, N);
}

// Round 5
// 388.235 us; speedup vs baseline: 3.4046x; 1.1076x over previous
//
#include <hip/hip_runtime.h>

#define N_RELS 16
#define N_BASES 8
#define HD 128
#define SCAN_B 1024

typedef __attribute__((ext_vector_type(8))) short bf16x8;
typedef __attribute__((ext_vector_type(4))) float floatx4;

__device__ __forceinline__ short bf16rn(float f) {
    union { float f; unsigned u; } v; v.f = f;
    unsigned u = v.u;
    unsigned r = (u + 0x7fffu + ((u >> 16) & 1u)) >> 16;
    return (short)r;
}

#define GLDS16(g, l)                                                            \
    __builtin_amdgcn_global_load_lds(                                           \
        (const __attribute__((address_space(1))) unsigned*)(g),                 \
        (__attribute__((address_space(3))) unsigned*)(l), 16, 0, 0)

// ---------------- dst counting-sort: hist -> scan -> scatter (CSR) ----------------

__global__ void hist_dst(const int* __restrict__ dst, int E, int* __restrict__ cnt) {
    int i = blockIdx.x * blockDim.x + threadIdx.x;
    if (i < E) atomicAdd(&cnt[dst[i]], 1);
}

__global__ void scan_partial(const int* __restrict__ cnt, int N,
                             int* __restrict__ excl, int* __restrict__ bsum) {
    __shared__ int s[SCAN_B];
    int t = threadIdx.x, i = blockIdx.x * SCAN_B + t;
    int v = (i < N) ? cnt[i] : 0;
    s[t] = v; __syncthreads();
    for (int o = 1; o < SCAN_B; o <<= 1) {
        int x = (t >= o) ? s[t - o] : 0;
        __syncthreads();
        s[t] += x;
        __syncthreads();
    }
    if (i < N) excl[i] = s[t] - v;
    if (t == SCAN_B - 1) bsum[blockIdx.x] = s[t];
}

__global__ void scan_bsum(int* __restrict__ bsum, int nb, int* __restrict__ row_ptr,
                          int N, int E) {
    if (threadIdx.x == 0 && blockIdx.x == 0) {
        int run = 0;
        for (int b = 0; b < nb; b++) { int x = bsum[b]; bsum[b] = run; run += x; }
        row_ptr[N] = E;
    }
}

__global__ void scan_fixup(int* __restrict__ row_ptr, const int* __restrict__ bsum,
                           int N, int* __restrict__ cursor) {
    int i = blockIdx.x * blockDim.x + threadIdx.x;
    if (i < N) { int v = row_ptr[i] + bsum[i >> 10]; row_ptr[i] = v; cursor[i] = v; }
}

// pack (etype, src) into one int: src < 65536
__global__ void scatter_dst(const int* __restrict__ dst, const int* __restrict__ src,
                            const int* __restrict__ et, const float* __restrict__ norm,
                            int E, int* __restrict__ cursor, int2* __restrict__ edata) {
    int i = blockIdx.x * blockDim.x + threadIdx.x;
    if (i >= E) return;
    int p = atomicAdd(&cursor[dst[i]], 1);
    edata[p] = make_int2((et[i] << 16) | src[i], __float_as_int(norm[i]));
}

// ---------------- pack fp32 rows -> bf16 pairs (one uint = 2 cols) ----------------

__global__ void pack_bf16(const float* __restrict__ x, unsigned* __restrict__ o, int n2) {
    int i = blockIdx.x * blockDim.x + threadIdx.x;
    if (i >= n2) return;
    float2 v = ((const float2*)x)[i];
    o[i] = ((unsigned)(unsigned short)bf16rn(v.y) << 16) | (unsigned short)bf16rn(v.x);
}

// ---------------- V[l][b] -> MFMA B-frag order, single bf16 ----------------
// frag: lane holds B[n=lane&15][k=(lane>>4)*8+j]; idx = ((kk*8+t)*64+lane)*8+j

__global__ void compute_V_frags(const float* __restrict__ V1, const float* __restrict__ V2,
                                short* __restrict__ Vf) {
    int blk = blockIdx.x;          // 0..15 = layer*8 + basis
    const float* V = ((blk & 8) ? V2 : V1) + (size_t)(blk & 7) * 16384;
    size_t obase = (size_t)blk * 16384;
    for (int e = threadIdx.x; e < 16384; e += blockDim.x) {
        float w = V[e];
        int k = e >> 7, n = e & 127;
        int kk = k >> 5, q = (k >> 3) & 3, j = k & 7;
        int lane = q * 16 + (n & 15);
        int idx = ((kk * 8 + (n >> 4)) * 64 + lane) * 8 + j;
        Vf[obase + idx] = bf16rn(w);
    }
}

// ---------------- phase 1: Z[d][b][:] = sum_e (coef[et,b]*norm) * hb[src] ----------------
// one wave per dst node; bf16 gathers, x4 unrolled independent loads; fp32 acc; bf16 store.

__global__ __launch_bounds__(256) void basis_agg(
    const unsigned* __restrict__ hb, const int2* __restrict__ edata,
    const int* __restrict__ row_ptr, const float* __restrict__ coef,
    unsigned* __restrict__ Z, int N) {
    __shared__ float cs[N_RELS * N_BASES];
    if (threadIdx.x < N_RELS * N_BASES) cs[threadIdx.x] = coef[threadIdx.x];
    __syncthreads();

    int wid = (blockIdx.x * blockDim.x + threadIdx.x) >> 6;
    int lane = threadIdx.x & 63;
    if (wid >= N) return;
    int e = row_ptr[wid], end = row_ptr[wid + 1];

    float2 acc[N_BASES] = {};
    auto proc = [&](int2 m, unsigned g) {
        float nv = __int_as_float(m.y);
        int et = m.x >> 16;
        float vx = __uint_as_float(g << 16);
        float vy = __uint_as_float(g & 0xffff0000u);
#pragma unroll
        for (int b = 0; b < N_BASES; b++) {
            float w = cs[et * N_BASES + b] * nv;
            acc[b].x = fmaf(vx, w, acc[b].x);
            acc[b].y = fmaf(vy, w, acc[b].y);
        }
    };

    for (; e + 4 <= end; e += 4) {
        int2 m0 = edata[e], m1 = edata[e + 1], m2 = edata[e + 2], m3 = edata[e + 3];
        unsigned g0 = hb[(size_t)(m0.x & 0xffff) * 64 + lane];
        unsigned g1 = hb[(size_t)(m1.x & 0xffff) * 64 + lane];
        unsigned g2 = hb[(size_t)(m2.x & 0xffff) * 64 + lane];
        unsigned g3 = hb[(size_t)(m3.x & 0xffff) * 64 + lane];
        proc(m0, g0); proc(m1, g1); proc(m2, g2); proc(m3, g3);
    }
    for (; e < end; e++) {
        int2 m = edata[e];
        unsigned g = hb[(size_t)(m.x & 0xffff) * 64 + lane];
        proc(m, g);
    }

    unsigned* zrow = Z + (size_t)wid * (N_BASES * 64) + lane;
#pragma unroll
    for (int b = 0; b < N_BASES; b++) {
        unsigned lo = (unsigned)(unsigned short)bf16rn(acc[b].x);
        unsigned hi = (unsigned)(unsigned short)bf16rn(acc[b].y);
        zrow[b * 64] = (hi << 16) | lo;
    }
}

// ---------------- phase 2: out[d] = bias + sum_b Z[d][b] @ V[b] ----------------
// block 256 (4 waves) x 2 m-tiles/wave = 128 rows/block; double-buffered B staging.
// mode 0: out = relu(acc+bias) -> bf16-packed h1.  mode 1: out = acc+bias -> fp32.

__global__ __launch_bounds__(256) void zb_gemm2(
    const unsigned short* __restrict__ Z, const short* __restrict__ Vf,
    const float* __restrict__ bias, void* __restrict__ outp, int N, int mode) {
    __shared__ __align__(16) short Bs[2][4][8][64][8];   // 2 x 32 KB
    const int t0 = threadIdx.x;
    const int wave = t0 >> 6, lane = t0 & 63;
    const int q = lane >> 4, cc = lane & 15;
    const int wl = wave * 64;
    const int ntiles = N / 16;                 // 3125
    int mt0 = blockIdx.x * 8 + wave * 2;
    int mt1 = mt0 + 1;
    const bool a0 = mt0 < ntiles, a1 = mt1 < ntiles;
    const int m0 = a0 ? mt0 : 0, m1 = a1 ? mt1 : 0;

    const unsigned short* z0 = Z + (size_t)(m0 * 16 + cc) * (N_BASES * HD);
    const unsigned short* z1 = Z + (size_t)(m1 * 16 + cc) * (N_BASES * HD);

    auto stage = [&](int b, int buf) {
        const short* g = Vf + (size_t)b * 16384;
        short* l = &Bs[buf][0][0][0][0];
#pragma unroll
        for (int i = 0; i < 8; i++)
            GLDS16(g + (size_t)(i * 256 + wl + lane) * 8, l + (size_t)(i * 256 + wl) * 8);
    };

    bf16x8 A0[4], A1[4], An0[4], An1[4];
#pragma unroll
    for (int kk = 0; kk < 4; kk++) {
        A0[kk] = *(const bf16x8*)(z0 + kk * 32 + q * 8);
        A1[kk] = *(const bf16x8*)(z1 + kk * 32 + q * 8);
    }
    stage(0, 0);

    floatx4 acc0[8] = {}, acc1[8] = {};
    for (int b = 0; b < N_BASES; b++) {
        __syncthreads();        // drains stage(b); all waves done reading buf[b&1] from b-2
        if (b < N_BASES - 1) {
            stage(b + 1, (b + 1) & 1);   // async; overlaps compute below
#pragma unroll
            for (int kk = 0; kk < 4; kk++) {
                An0[kk] = *(const bf16x8*)(z0 + (b + 1) * HD + kk * 32 + q * 8);
                An1[kk] = *(const bf16x8*)(z1 + (b + 1) * HD + kk * 32 + q * 8);
            }
        }
#pragma unroll
        for (int kk = 0; kk < 4; kk++) {
#pragma unroll
            for (int t = 0; t < 8; t++) {
                bf16x8 B = *(const bf16x8*)&Bs[b & 1][kk][t][lane][0];
                acc0[t] = __builtin_amdgcn_mfma_f32_16x16x32_bf16(A0[kk], B, acc0[t], 0, 0, 0);
                acc1[t] = __builtin_amdgcn_mfma_f32_16x16x32_bf16(A1[kk], B, acc1[t], 0, 0, 0);
            }
        }
        if (b < N_BASES - 1) {
#pragma unroll
            for (int kk = 0; kk < 4; kk++) { A0[kk] = An0[kk]; A1[kk] = An1[kk]; }
        }
    }

    // C/D layout: col = t*16 + cc, row = q*4 + i
    float bv[8];
#pragma unroll
    for (int t = 0; t < 8; t++) bv[t] = bias[t * 16 + cc];

    if (mode == 0) {
        unsigned short* o = (unsigned short*)outp;
#pragma unroll
        for (int mi = 0; mi < 2; mi++) {
            if (mi ? !a1 : !a0) continue;
            int mt = mi ? m1 : m0;
            floatx4* ac = mi ? acc1 : acc0;
#pragma unroll
            for (int t = 0; t < 8; t++)
#pragma unroll
                for (int i = 0; i < 4; i++) {
                    float v = fmaxf(ac[t][i] + bv[t], 0.f);
                    o[(size_t)(mt * 16 + q * 4 + i) * HD + t * 16 + cc] =
                        (unsigned short)bf16rn(v);
                }
        }
    } else {
        float* o = (float*)outp;
#pragma unroll
        for (int mi = 0; mi < 2; mi++) {
            if (mi ? !a1 : !a0) continue;
            int mt = mi ? m1 : m0;
            floatx4* ac = mi ? acc1 : acc0;
#pragma unroll
            for (int t = 0; t < 8; t++)
#pragma unroll
                for (int i = 0; i < 4; i++)
                    o[(size_t)(mt * 16 + q * 4 + i) * HD + t * 16 + cc] = ac[t][i] + bv[t];
        }
    }
}

// ---------------- launch ----------------

extern "C" void kernel_launch(void* const* d_in, const int* in_sizes, int n_in,
                              void* d_out, int out_size, void* d_ws, size_t ws_size,
                              hipStream_t stream) {
    const float* h     = (const float*)d_in[0];
    const float* norm  = (const float*)d_in[1];
    const int*   src   = (const int*)d_in[2];
    const int*   dst   = (const int*)d_in[3];
    const int*   etype = (const int*)d_in[4];
    const float* V1    = (const float*)d_in[5];
    const float* coef1 = (const float*)d_in[6];
    const float* bias1 = (const float*)d_in[7];
    const float* V2    = (const float*)d_in[8];
    const float* coef2 = (const float*)d_in[9];
    const float* bias2 = (const float*)d_in[10];
    const int N = in_sizes[0] / HD;   // 50000
    const int E = in_sizes[2];        // 640000
    float* out = (float*)d_out;
    (void)n_in; (void)out_size; (void)ws_size;

    char* ws = (char*)d_ws;
    size_t off = 0;
    auto alloc = [&](size_t bytes) {
        void* p = ws + off;
        off += (bytes + 255) & ~(size_t)255;
        return p;
    };
    short*    Vf      = (short*)alloc((size_t)16 * 16384 * sizeof(short));  // 512 KB
    unsigned* hb      = (unsigned*)alloc((size_t)N * 64 * sizeof(unsigned)); // 12.8 MB
    unsigned* h1b     = (unsigned*)alloc((size_t)N * 64 * sizeof(unsigned)); // 12.8 MB
    int2*     edata   = (int2*)alloc((size_t)E * sizeof(int2));
    int*      cnt     = (int*)alloc((size_t)N * sizeof(int));
    int*      row_ptr = (int*)alloc((size_t)(N + 1) * sizeof(int));
    int*      cursor  = (int*)alloc((size_t)N * sizeof(int));
    int*      bsum    = (int*)alloc(256 * sizeof(int));
    unsigned* Z       = (unsigned*)alloc((size_t)N * N_BASES * 64 * sizeof(unsigned)); // 102.4 MB

    const int nb = (N + SCAN_B - 1) / SCAN_B;

    hipMemsetAsync(cnt, 0, (size_t)N * sizeof(int), stream);
    hist_dst<<<(E + 255) / 256, 256, 0, stream>>>(dst, E, cnt);
    scan_partial<<<nb, SCAN_B, 0, stream>>>(cnt, N, row_ptr, bsum);
    scan_bsum<<<1, 64, 0, stream>>>(bsum, nb, row_ptr, N, E);
    scan_fixup<<<(N + 255) / 256, 256, 0, stream>>>(row_ptr, bsum, N, cursor);
    scatter_dst<<<(E + 255) / 256, 256, 0, stream>>>(dst, src, etype, norm, E, cursor, edata);
    compute_V_frags<<<16, 256, 0, stream>>>(V1, V2, Vf);
    pack_bf16<<<(N * 64 + 255) / 256, 256, 0, stream>>>(h, hb, N * 64);

    const int aggblocks  = (N * 64 + 255) / 256;          // 12500
    const int gemmblocks = ((N / 16) + 7) / 8;            // 391

    // layer 1: h1b = bf16(relu(bias1 + sum_b Z_b @ V1_b))
    basis_agg<<<aggblocks, 256, 0, stream>>>(hb, edata, row_ptr, coef1, Z, N);
    zb_gemm2<<<gemmblocks, 256, 0, stream>>>((const unsigned short*)Z, Vf, bias1, h1b, N, 0);
    // layer 2: out = bias2 + sum_b Z_b(h1b) @ V2_b
    basis_agg<<<aggblocks, 256, 0, stream>>>(h1b, edata, row_ptr, coef2, Z, N);
    zb_gemm2<<<gemmblocks, 256, 0, stream>>>((const unsigned short*)Z, Vf + (size_t)8 * 16384,
                                             bias2, out, N, 1);
}